// Round 7
// baseline (7534.766 us; speedup 1.0000x reference)
//
#include <hip/hip_runtime.h>
#include <math.h>

// RNNActor — bisection round 7: INDEPENDENT re-implementation of the upstream
// (encoder + gate GEMM), boring tiled GEMMs reading W_ih directly (transpose
// in LDS). Trusted backend from r6 (k_prep2, k_lstm_simple, k_head) verbatim.
// T=512 B=512 D_IN=128 D_HID=512 D_RNN=128 D_ACT=16
//
// ws layout:
//   hS, cS  512*128 f32      (persistent LSTM state)
//   W_hhT   128*512 f32      (W_hh^T for simple LSTM)
//   featc   CH*512*512 f32   (encoder output, chunk-local)
//   gbuf    CH*512*512 f32   (gate pre-activations, chunk-local)
//   hsc     CH*512*128 f32   (h outputs, chunk-local)

#define LOG_2PI 1.8378770664093453f

__device__ __forceinline__ float sigf(float x) {
    float e = expf(-fabsf(x));
    float r = 1.0f / (1.0f + e);
    return x >= 0.f ? r : e * r;
}

// ---------------------------------------------------------------- k_init
// hS=h0, cS=c0, log_prob = const fill. Nothing else.
__global__ __launch_bounds__(256) void k_init(const float* __restrict__ h0,
                                              const float* __restrict__ c0,
                                              const float* __restrict__ log_std,
                                              float* __restrict__ hS,
                                              float* __restrict__ cS,
                                              float* __restrict__ log_prob) {
    const int gid = blockIdx.x * 256 + threadIdx.x;   // 0..65535
    hS[gid] = h0[gid];
    cS[gid] = c0[gid];
    float ssum = 0.f;
    #pragma unroll
    for (int a = 0; a < 16; ++a) ssum += log_std[a];
    const float lpc = -ssum - 8.0f * LOG_2PI;
    #pragma unroll
    for (int q = 0; q < 4; ++q) log_prob[gid + q * 65536] = lpc;
}

// ---------------------------------------------------------------- k_prep2
// W_hhT[k][j] = W_hh[j][k]  (W_hh [512][128] -> W_hhT [128][512])  [r6, trusted]
__global__ __launch_bounds__(256) void k_prep2(const float* __restrict__ W_hh,
                                               float* __restrict__ W_hhT) {
    __shared__ float tile[32][33];
    const int bid = blockIdx.x;          // 64 blocks = 16 rowblk x 4 colblk
    const int j0 = (bid >> 2) * 32;
    const int k0 = (bid & 3) * 32;
    const int t = threadIdx.x;
    const int i = t >> 3, c4 = t & 7;
    float4 v = *(const float4*)&W_hh[(size_t)(j0 + i) * 128 + k0 + 4 * c4];
    tile[i][4 * c4 + 0] = v.x; tile[i][4 * c4 + 1] = v.y;
    tile[i][4 * c4 + 2] = v.z; tile[i][4 * c4 + 3] = v.w;
    __syncthreads();
    float4 o;
    o.x = tile[4 * c4 + 0][i]; o.y = tile[4 * c4 + 1][i];
    o.z = tile[4 * c4 + 2][i]; o.w = tile[4 * c4 + 3][i];
    *(float4*)&W_hhT[(size_t)(k0 + i) * 512 + j0 + 4 * c4] = o;
}

// ---------------------------------------------------------------- k_feat
// featc[r][c] = tanh(obs[row0+r][:] @ W_enc[:][c] + b_enc[c]).
// Boring tiled GEMM: 32 rows x 64 cols per block, K-step 32, padded LDS,
// scalar staging, no pipeline. Thread: col c (t&63), row-group rg (t>>6).
__global__ __launch_bounds__(256) void k_feat(const float* __restrict__ obs,
                                              const float* __restrict__ W_enc,
                                              const float* __restrict__ b_enc,
                                              float* __restrict__ featc,
                                              int row0) {
    __shared__ float As[32][33];
    __shared__ float Bs[32][65];
    const int bid = blockIdx.x;
    const int r0 = (bid >> 3) * 32;            // chunk-local row base
    const int c0g = (bid & 7) * 64;
    const int t = threadIdx.x;
    const int c = t & 63, rg = t >> 6;
    float acc[8];
    #pragma unroll
    for (int rr = 0; rr < 8; ++rr) acc[rr] = 0.f;

    for (int k0 = 0; k0 < 128; k0 += 32) {
        #pragma unroll
        for (int i = 0; i < 4; ++i) {          // 1024 elems of obs tile
            int idx = t + 256 * i;
            int r = idx >> 5, kk = idx & 31;
            As[r][kk] = obs[(size_t)(row0 + r0 + r) * 128 + k0 + kk];
        }
        #pragma unroll
        for (int i = 0; i < 8; ++i) {          // 2048 elems of W_enc tile
            int idx = t + 256 * i;
            int kk = idx >> 6, cc = idx & 63;
            Bs[kk][cc] = W_enc[(size_t)(k0 + kk) * 512 + c0g + cc];
        }
        __syncthreads();
        for (int kk = 0; kk < 32; ++kk) {
            float b = Bs[kk][c];
            #pragma unroll
            for (int rr = 0; rr < 8; ++rr)
                acc[rr] = fmaf(As[rg * 8 + rr][kk], b, acc[rr]);
        }
        __syncthreads();
    }
    const float be = b_enc[c0g + c];
    #pragma unroll
    for (int rr = 0; rr < 8; ++rr)
        featc[(size_t)(r0 + rg * 8 + rr) * 512 + c0g + c] = tanhf(acc[rr] + be);
}

// ---------------------------------------------------------------- k_gates
// gbuf[r][j] = featc[r][:] @ W_ih[j][:] + b_ih[j] + b_hh[j].
// W_ih read DIRECTLY (transpose happens in the LDS staging). Same tile shape.
__global__ __launch_bounds__(256) void k_gates(const float* __restrict__ featc,
                                               const float* __restrict__ W_ih,
                                               const float* __restrict__ b_ih,
                                               const float* __restrict__ b_hh,
                                               float* __restrict__ gbuf) {
    __shared__ float As[32][33];
    __shared__ float Bs[32][65];
    const int bid = blockIdx.x;
    const int r0 = (bid >> 3) * 32;            // chunk-local row base
    const int j0g = (bid & 7) * 64;
    const int t = threadIdx.x;
    const int c = t & 63, rg = t >> 6;
    float acc[8];
    #pragma unroll
    for (int rr = 0; rr < 8; ++rr) acc[rr] = 0.f;

    for (int k0 = 0; k0 < 512; k0 += 32) {
        #pragma unroll
        for (int i = 0; i < 4; ++i) {          // 1024 elems of feat tile
            int idx = t + 256 * i;
            int r = idx >> 5, kk = idx & 31;
            As[r][kk] = featc[(size_t)(r0 + r) * 512 + k0 + kk];
        }
        #pragma unroll
        for (int i = 0; i < 8; ++i) {          // 2048 elems of W_ih tile, transposed
            int idx = t + 256 * i;
            int j = idx >> 5, kk = idx & 31;   // kk consecutive -> coalesced
            Bs[kk][j] = W_ih[(size_t)(j0g + j) * 512 + k0 + kk];
        }
        __syncthreads();
        for (int kk = 0; kk < 32; ++kk) {
            float b = Bs[kk][c];
            #pragma unroll
            for (int rr = 0; rr < 8; ++rr)
                acc[rr] = fmaf(As[rg * 8 + rr][kk], b, acc[rr]);
        }
        __syncthreads();
    }
    const float bb = b_ih[j0g + c] + b_hh[j0g + c];
    #pragma unroll
    for (int rr = 0; rr < 8; ++rr)
        gbuf[(size_t)(r0 + rg * 8 + rr) * 512 + j0g + c] = acc[rr] + bb;
}

// ---------------------------------------------------------------- k_lstm_simple  [r6, trusted]
__global__ __launch_bounds__(512) void k_lstm_simple(const float* __restrict__ gbuf,
                                                     const float* __restrict__ done,
                                                     const float* __restrict__ W_hhT,
                                                     float* __restrict__ hS,
                                                     float* __restrict__ cS,
                                                     float* __restrict__ hsc,
                                                     float* __restrict__ hT,
                                                     float* __restrict__ cT,
                                                     int st0, int CH) {
    __shared__ float hL[2][128];
    __shared__ float hmL[2][128];
    __shared__ float gatesL[2][512];
    const int bid = blockIdx.x;
    const int t = threadIdx.x;
    const int bg0 = bid * 2;
    const bool upd = (t < 256);
    const int ub = (t >> 7) & 1;
    const int uk = t & 127;
    float creg = 0.f;
    if (upd) {
        hL[ub][uk] = hS[(size_t)(bg0 + ub) * 128 + uk];
        creg = cS[(size_t)(bg0 + ub) * 128 + uk];
    }
    __syncthreads();

    for (int s = 0; s < CH; ++s) {
        const int st = st0 + s;
        const float m0 = 1.0f - done[(size_t)st * 512 + bg0];
        const float m1 = 1.0f - done[(size_t)st * 512 + bg0 + 1];
        if (upd) hmL[ub][uk] = hL[ub][uk] * (ub ? m1 : m0);
        __syncthreads();

        float ga0 = gbuf[((size_t)(s * 512 + bg0)) * 512 + t];
        float ga1 = gbuf[((size_t)(s * 512 + bg0 + 1)) * 512 + t];
        #pragma unroll 16
        for (int k = 0; k < 128; ++k) {
            const float wv = W_hhT[(size_t)k * 512 + t];
            ga0 = fmaf(hmL[0][k], wv, ga0);
            ga1 = fmaf(hmL[1][k], wv, ga1);
        }
        gatesL[0][t] = ga0;
        gatesL[1][t] = ga1;
        __syncthreads();

        if (upd) {
            const float ig = sigf(gatesL[ub][uk]);
            const float fg = sigf(gatesL[ub][128 + uk]);
            const float gg = tanhf(gatesL[ub][256 + uk]);
            const float og = sigf(gatesL[ub][384 + uk]);
            const float mm = ub ? m1 : m0;
            creg = fg * (creg * mm) + ig * gg;
            const float hh = og * tanhf(creg);
            hL[ub][uk] = hh;
            hsc[((size_t)(s * 512 + bg0 + ub)) * 128 + uk] = hh;
            if (s == CH - 1) {
                hS[(size_t)(bg0 + ub) * 128 + uk] = hh;
                cS[(size_t)(bg0 + ub) * 128 + uk] = creg;
            }
            if (st == 511) {
                hT[(size_t)(bg0 + ub) * 128 + uk] = hh;
                cT[(size_t)(bg0 + ub) * 128 + uk] = creg;
            }
        }
        __syncthreads();
    }
}

// ---------------------------------------------------------------- k_head  [r6, trusted]
__global__ __launch_bounds__(256) void k_head(const float* __restrict__ hsc,
                                              const float* __restrict__ W_mean,
                                              const float* __restrict__ b_mean,
                                              float* __restrict__ action,
                                              int st0) {
    __shared__ __align__(16) float hsT[64][132];
    __shared__ __align__(16) float wm[128][16];
    const int r0 = blockIdx.x * 64;                     // chunk-local row base
    const int t = threadIdx.x;
    #pragma unroll
    for (int i = 0; i < 8; ++i) {
        int f = t + 256 * i;
        int rr = f >> 5, cc = (f & 31) * 4;
        *(float4*)&hsT[rr][cc] = *(const float4*)&hsc[(size_t)(r0 + rr) * 128 + cc];
    }
    #pragma unroll
    for (int i = 0; i < 2; ++i) {
        int f = t + 256 * i;
        int rr = f >> 2, cc = (f & 3) * 4;
        float4 v = *(const float4*)&W_mean[(size_t)f * 4];
        *(float4*)&wm[rr][cc] = v;
    }
    __syncthreads();
    const int r = t >> 2, q = t & 3;
    float acc[4];
    { float4 bm = *(const float4*)&b_mean[q * 4];
      acc[0] = bm.x; acc[1] = bm.y; acc[2] = bm.z; acc[3] = bm.w; }
    #pragma unroll 8
    for (int k = 0; k < 128; ++k) {
        float s = hsT[r][k];
        float4 wv = *(const float4*)&wm[k][q * 4];
        acc[0] = fmaf(s, wv.x, acc[0]);
        acc[1] = fmaf(s, wv.y, acc[1]);
        acc[2] = fmaf(s, wv.z, acc[2]);
        acc[3] = fmaf(s, wv.w, acc[3]);
    }
    *(float4*)&action[((size_t)st0 * 512 + r0 + r) * 16 + q * 4] =
        make_float4(acc[0], acc[1], acc[2], acc[3]);
}

// ---------------------------------------------------------------- launch
extern "C" void kernel_launch(void* const* d_in, const int* in_sizes, int n_in,
                              void* d_out, int out_size, void* d_ws, size_t ws_size,
                              hipStream_t stream) {
    const float* obs     = (const float*)d_in[0];
    const float* h0      = (const float*)d_in[1];
    const float* c0      = (const float*)d_in[2];
    const float* done    = (const float*)d_in[3];
    const float* W_enc   = (const float*)d_in[4];
    const float* b_enc   = (const float*)d_in[5];
    const float* W_ih    = (const float*)d_in[6];
    const float* W_hh    = (const float*)d_in[7];
    const float* b_ih    = (const float*)d_in[8];
    const float* b_hh    = (const float*)d_in[9];
    const float* W_mean  = (const float*)d_in[10];
    const float* b_mean  = (const float*)d_in[11];
    const float* log_std = (const float*)d_in[12];

    float* out      = (float*)d_out;
    float* action   = out;                       // 262144*16
    float* log_prob = out + 4194304;             // 262144
    float* hT       = out + 4194304 + 262144;    // 65536
    float* cT       = hT + 65536;                // 65536

    char* ws = (char*)d_ws;
    size_t off = 0;
    float* hS    = (float*)(ws + off); off += 65536 * 4;       // 256 KB
    float* cS    = (float*)(ws + off); off += 65536 * 4;       // 256 KB
    float* W_hhT = (float*)(ws + off); off += 65536 * 4;       // 256 KB

    // adaptive chunk: CH steps need CH*(1 MiB feat + 1 MiB gates + 256 KiB hs)
    const size_t remain = (ws_size > off) ? (ws_size - off) : 0;
    int CH = 512;
    while (CH > 1 && (size_t)CH * (2u * 1048576u + 262144u) > remain) CH >>= 1;
    float* featc = (float*)(ws + off);                 // CH*262144 floats
    float* gbuf  = featc + (size_t)CH * 262144;        // CH*262144 floats
    float* hsc   = gbuf + (size_t)CH * 262144;         // CH*65536 floats

    k_init<<<256, 256, 0, stream>>>(h0, c0, log_std, hS, cS, log_prob);
    k_prep2<<<64, 256, 0, stream>>>(W_hh, W_hhT);
    for (int st0 = 0; st0 < 512; st0 += CH) {
        k_feat<<<CH * 128, 256, 0, stream>>>(obs, W_enc, b_enc, featc, st0 * 512);
        k_gates<<<CH * 128, 256, 0, stream>>>(featc, W_ih, b_ih, b_hh, gbuf);
        k_lstm_simple<<<256, 512, 0, stream>>>(gbuf, done, W_hhT,
                                               hS, cS, hsc, hT, cT, st0, CH);
        k_head<<<CH * 8, 256, 0, stream>>>(hsc, W_mean, b_mean, action, st0);
    }
}